// Round 6
// baseline (287.011 us; speedup 1.0000x reference)
//
#include <hip/hip_runtime.h>

#define TB 512
#define TF 1280
#define TH 2560
#define TK 8
#define TE 9

typedef unsigned short ushortT;
typedef unsigned long long u64;
typedef __attribute__((ext_vector_type(8))) short short8;
typedef __attribute__((ext_vector_type(4))) float floatx4;

__device__ __forceinline__ unsigned short f2bf(float f) {
  union { float f; unsigned u; } v; v.f = f;
  unsigned r = v.u + 0x7fffu + ((v.u >> 16) & 1u);   // RNE
  return (unsigned short)(r >> 16);
}

// pack two fp32 -> (bf16(a) low, bf16(b) high), RNE, via v_perm
__device__ __forceinline__ unsigned pk2(float a, float b) {
  union { float f; unsigned u; } ua, ub; ua.f = a; ub.f = b;
  unsigned ra = ua.u + 0x7fffu + ((ua.u >> 16) & 1u);
  unsigned rb = ub.u + 0x7fffu + ((ub.u >> 16) & 1u);
  return __builtin_amdgcn_perm(rb, ra, 0x07060302);  // {ra[31:16], rb[31:16]}
}

__device__ __forceinline__ void gl_lds16(const void* g, void* l) {
  __builtin_amdgcn_global_load_lds(
      (const __attribute__((address_space(1))) unsigned*)g,
      (__attribute__((address_space(3))) unsigned*)l, 16, 0, 0);
}

// ---- prepass: x -> bf16 k-quad [k/4][m][4], W2 -> bf16 transposed [e][n][h]
__global__ __launch_bounds__(256) void prepass(
    const float* __restrict__ x, const float* __restrict__ W2,
    u64* __restrict__ xq, ushortT* __restrict__ W2t) {
  const int i = blockIdx.x * 256 + threadIdx.x;
  if (i < 320 * 512) {                        // 163840 u64 of xq
    const int kq = i >> 9, m = i & 511;
    floatx4 v = *(const floatx4*)(x + (long)m * TF + kq * 4);
    xq[i] = (u64)pk2(v.x, v.y) | ((u64)pk2(v.z, v.w) << 32);
  } else {
    const int o = i - 320 * 512;
    if (o < TE * TK * TH) {                   // 184320 elements of W2t
      const int hcol = o % TH;
      const int rest = o / TH;
      const int n = rest & 7;
      const int e = rest >> 3;
      W2t[(long)(e * TK + n) * TH + hcol] = f2bf(W2[((long)e * TH + hcol) * TK + n]);
    }
  }
}

// ---- gemm1_fused: logits_acc += relu(x @ W1 + b1) @ W2   (no h materialized)
// BM=128 BN=128 BK=32; 4 waves (2x2), 4x4 frags of 16x16x32.
// A: bf16 xq via global_load_lds, DOUBLE-buffered LDS (prefetch spans compute).
// B: fp32 W1 -> regs (issued post-barrier-B, consumed post-barrier-A of next
//    iter => full compute phase in flight) -> pk2 -> k-quad LDS.
// Epilogue: bias+relu -> bf16 h-tile in LDS -> 8 MFMAs vs W2t -> atomicAdd.
__global__ __launch_bounds__(256) void gemm1_fused(
    const u64* __restrict__ xq, const float* __restrict__ W1,
    const float* __restrict__ b1, const ushortT* __restrict__ W2t,
    float* __restrict__ logacc) {
  __shared__ __align__(16) char smem[34816];
  u64* Aq0 = (u64*)smem;                  //  8448 B
  u64* Aq1 = (u64*)(smem + 8448);         //  8448 B
  u64* Bq  = (u64*)(smem + 16896);        //  8448 B   (25344 total in-loop)
  ushortT* Ht = (ushortT*)smem;           // 34816 B   (epilogue reuse, ld=136)

  const int t = threadIdx.x;
  const int lane = t & 63, w = t >> 6;
  const int bid = blockIdx.x;
  const int mt = bid & 3;                 // m-siblings adjacent: W1 slab shared
  const int ctile = bid >> 2;
  const int e = ctile / 20;
  const int hbase = (ctile % 20) * 128;
  const int m0 = mt * 128;
  const int wm = w & 1, wn = w >> 1;
  const int lm = lane & 15, lq = lane >> 4;

  // B reg-load mapping: half-wave rows, 512B contiguous per k-row
  const int n4 = (t & 31) * 4;            // n offset 0..124
  const int kq = t >> 5;                  // k-quad row 0..7
  const float* bgl = W1 + ((long)e * TF + kq * 4) * TH + hbase + n4;

  const u64* agB = xq + m0 + lane * 2;    // + kqrow*512

  floatx4 acc[4][4];
#pragma unroll
  for (int i = 0; i < 4; ++i)
#pragma unroll
    for (int j = 0; j < 4; ++j) acc[i][j] = (floatx4){0.f, 0.f, 0.f, 0.f};

  floatx4 bv[2][4];

  auto ldB = [&](int buf, int kt) {
#pragma unroll
    for (int i = 0; i < 4; ++i)
      bv[buf][i] = *(const floatx4*)(bgl + ((long)kt * 32 + i) * TH);
  };
  auto ldA = [&](u64* Adst, int kt) {
    gl_lds16(agB + (long)(kt * 8 + w) * 512, &Adst[w * 132]);
    gl_lds16(agB + (long)(kt * 8 + w + 4) * 512, &Adst[(w + 4) * 132]);
  };

  // prologue: tile 0 in flight
  ldB(0, 0);
  ldA(Aq0, 0);

  for (int kt = 0; kt < 40; ++kt) {
    const int c = kt & 1;
    if (kt) __syncthreads();              // barrier A: readers of kt-1 done;
                                          // drains bv(kt) + A(kt) (full-iter cover)
    {                                     // convert + stage B(kt)
      u64 q[4];
#pragma unroll
      for (int n = 0; n < 4; ++n)
        q[n] = (u64)pk2(bv[c][0][n], bv[c][1][n]) |
               ((u64)pk2(bv[c][2][n], bv[c][3][n]) << 32);
      *(ulonglong2*)&Bq[kq * 132 + n4]     = make_ulonglong2(q[0], q[1]);
      *(ulonglong2*)&Bq[kq * 132 + n4 + 2] = make_ulonglong2(q[2], q[3]);
    }
    __syncthreads();                      // barrier B: staging visible
    if (kt < 39) {                        // prefetch tile kt+1 (covered by compute)
      ldB(c ^ 1, kt + 1);
      ldA((kt & 1) ? Aq0 : Aq1, kt + 1);
    }
    const u64* Acur = (kt & 1) ? Aq1 : Aq0;

    short8 af[4], bf[4];
#pragma unroll
    for (int mg = 0; mg < 4; ++mg) {
      const int m = wm * 64 + mg * 16 + lm;
      ((u64*)&af[mg])[0] = Acur[(2 * lq) * 132 + m];
      ((u64*)&af[mg])[1] = Acur[(2 * lq + 1) * 132 + m];
    }
#pragma unroll
    for (int ng = 0; ng < 4; ++ng) {
      const int n = wn * 64 + ng * 16 + lm;
      ((u64*)&bf[ng])[0] = Bq[(2 * lq) * 132 + n];
      ((u64*)&bf[ng])[1] = Bq[(2 * lq + 1) * 132 + n];
    }
#pragma unroll
    for (int mg = 0; mg < 4; ++mg)
#pragma unroll
      for (int ng = 0; ng < 4; ++ng)
        acc[mg][ng] = __builtin_amdgcn_mfma_f32_16x16x32_bf16(af[mg], bf[ng], acc[mg][ng], 0, 0, 0);
  }

  // ---- fused epilogue ----
  float b1v[4];
#pragma unroll
  for (int ng = 0; ng < 4; ++ng)
    b1v[ng] = b1[e * TH + hbase + wn * 64 + ng * 16 + lm];

  __syncthreads();                        // done with Aq/Bq; Ht overwrites
  // h-tile (bias+relu, bf16) -> Ht[row][col], ld=136
#pragma unroll
  for (int mg = 0; mg < 4; ++mg) {
    const int rbase = wm * 64 + mg * 16 + lq * 4;
#pragma unroll
    for (int ng = 0; ng < 4; ++ng) {
      const int col = wn * 64 + ng * 16 + lm;
      floatx4 cv = acc[mg][ng];
#pragma unroll
      for (int r = 0; r < 4; ++r) {
        float v = cv[r] + b1v[ng];
        v = v > 0.f ? v : 0.f;
        Ht[(rbase + r) * 136 + col] = f2bf(v);
      }
    }
  }
  __syncthreads();

  // gemm2 partial: D[j][row] = sum_col W2t[e][j][col] * h[row][col]
#pragma unroll
  for (int g = 0; g < 2; ++g) {
    const int rgb = w * 32 + g * 16;      // 16-row group per wave
    floatx4 d = (floatx4){0.f, 0.f, 0.f, 0.f};
#pragma unroll
    for (int kc = 0; kc < 4; ++kc) {
      short8 a;
      if (lm < 8)
        a = *(const short8*)(W2t + ((long)(e * TK + lm)) * TH + hbase + kc * 32 + lq * 8);
      else
        a = (short8){0, 0, 0, 0, 0, 0, 0, 0};
      short8 bfrag = *(const short8*)&Ht[(rgb + lm) * 136 + kc * 32 + lq * 8];
      d = __builtin_amdgcn_mfma_f32_16x16x32_bf16(a, bfrag, d, 0, 0, 0);
    }
    // D layout: lane holds row=rgb+lm (n), j=lq*4+r (m); j valid for lq<2
    if (lq < 2) {
#pragma unroll
      for (int r = 0; r < 4; ++r)
        atomicAdd(&logacc[((long)e * TB + m0 + rgb + lm) * TK + lq * 4 + r], d[r]);
    }
  }
}

// ---- softmax + leaf products + logits output -------------------------------
__global__ __launch_bounds__(256) void softmax_leaf(
    const float* __restrict__ logacc, const float* __restrict__ b2,
    float* __restrict__ out, float* __restrict__ logits_out) {
  const int b = blockIdx.x * 256 + threadIdx.x;
  if (b >= TB) return;
  float p0[8];
  out[(long)b * 73] = 1.0f;
#pragma unroll
  for (int e = 0; e < TE; ++e) {
    float v[8], mx = -1e30f;
#pragma unroll
    for (int j = 0; j < 8; ++j) {
      v[j] = logacc[((long)e * TB + b) * TK + j] + b2[e * TK + j];
      logits_out[((long)e * TB + b) * TK + j] = v[j];
      mx = fmaxf(mx, v[j]);
    }
    float sm = 0.f;
#pragma unroll
    for (int j = 0; j < 8; ++j) { v[j] = __expf(v[j] - mx); sm += v[j]; }
    const float inv = 1.0f / sm;
    if (e == 0) {
#pragma unroll
      for (int j = 0; j < 8; ++j) {
        p0[j] = v[j] * inv;
        out[(long)b * 73 + 1 + j] = p0[j];
      }
    } else {
      const float pp = p0[e - 1];
#pragma unroll
      for (int j = 0; j < 8; ++j)
        out[(long)b * 73 + 9 + (e - 1) * 8 + j] = pp * v[j] * inv;
    }
  }
}

extern "C" void kernel_launch(void* const* d_in, const int* in_sizes, int n_in,
                              void* d_out, int out_size, void* d_ws, size_t ws_size,
                              hipStream_t stream) {
  const float* x  = (const float*)d_in[0];
  const float* W1 = (const float*)d_in[1];
  const float* b1 = (const float*)d_in[2];
  const float* W2 = (const float*)d_in[3];
  const float* b2 = (const float*)d_in[4];
  float* out = (float*)d_out;

  // ws layout (tiny now)
  float*   logacc = (float*)d_ws;                        //   147,456 B
  u64*     xq     = (u64*)((char*)d_ws + 147456);        // 1,310,720 B
  ushortT* W2t    = (ushortT*)((char*)d_ws + 1458176);   //   368,640 B
  float* logits_out = out + TB * 73;

  hipMemsetAsync(logacc, 0, (size_t)TE * TB * TK * sizeof(float), stream);
  prepass<<<1360, 256, 0, stream>>>(x, W2, xq, W2t);
  gemm1_fused<<<720, 256, 0, stream>>>(xq, W1, b1, W2t, logacc);
  softmax_leaf<<<2, 256, 0, stream>>>(logacc, b2, out, logits_out);
}